// Round 1
// baseline (20634.659 us; speedup 1.0000x reference)
//
#include <hip/hip_runtime.h>
#include <hip/hip_cooperative_groups.h>

namespace cg = cooperative_groups;

typedef _Float16 half8 __attribute__((ext_vector_type(8)));
typedef _Float16 half4v __attribute__((ext_vector_type(4)));
typedef float f32x4 __attribute__((ext_vector_type(4)));

#define T_STEPS 1024
#define BB 64
#define HH 512
#define K2 1024   // 2H
#define NWG 32    // one wg per 16 hidden units

// ---------------- prep: fp32 -> fp16 conversions + W fragment packing ----------------
// w16 layout: [wg][gate][kb][lane][8] halves, exactly the B-fragment order for
// v_mfma_f32_16x16x32_f16: B[k][j] with j = gate*512 + wg*16 + (lane&15),
// k = kb*32 + (lane>>4)*8 + e.
__global__ __launch_bounds__(256) void prep_kernel(
    const float* __restrict__ x, const float* __restrict__ h0,
    const float* __restrict__ W, _Float16* __restrict__ x16,
    _Float16* __restrict__ h16, _Float16* __restrict__ w16)
{
  const long nthr = (long)gridDim.x * blockDim.x;
  const long tid  = (long)blockIdx.x * blockDim.x + threadIdx.x;

  // x: T*B*H = 33,554,432 elems = 8,388,608 float4
  for (long p = tid; p < 8388608L; p += nthr) {
    float4 v = ((const float4*)x)[p];
    half4v o;
    o[0] = (_Float16)v.x; o[1] = (_Float16)v.y;
    o[2] = (_Float16)v.z; o[3] = (_Float16)v.w;
    *(half4v*)(x16 + p*4) = o;
  }
  // h0 -> h16 buffer 0: 32768 elems = 8192 float4
  for (long p = tid; p < 8192L; p += nthr) {
    float4 v = ((const float4*)h0)[p];
    half4v o;
    o[0] = (_Float16)v.x; o[1] = (_Float16)v.y;
    o[2] = (_Float16)v.z; o[3] = (_Float16)v.w;
    *(half4v*)(h16 + p*4) = o;
  }
  // W pack: 32*4*32*64 = 262,144 fragments of 8 halves
  for (long p = tid; p < 262144L; p += nthr) {
    int lane = (int)(p & 63);
    int kb   = (int)((p >> 6) & 31);
    int g    = (int)((p >> 11) & 3);
    int wg   = (int)(p >> 13);
    int j = g*512 + wg*16 + (lane & 15);
    int k = kb*32 + (lane >> 4)*8;
    const float* src = W + (long)j*K2 + k;
    float4 a = *(const float4*)(src);
    float4 b = *(const float4*)(src + 4);
    half8 o;
    o[0] = (_Float16)a.x; o[1] = (_Float16)a.y; o[2] = (_Float16)a.z; o[3] = (_Float16)a.w;
    o[4] = (_Float16)b.x; o[5] = (_Float16)b.y; o[6] = (_Float16)b.z; o[7] = (_Float16)b.w;
    *(half8*)(w16 + p*8) = o;
  }
}

// ---------------- persistent cooperative LSTM core ----------------
// 32 wgs x 256 threads. wg owns hidden units [wg*16, wg*16+16) for all 64 batch rows.
// Wave v owns batch rows [v*16, v*16+16): computes 4 gate tiles (16x16) with K=1024,
// combines gates locally, keeps c in registers (C-fragment layout).
__global__ __launch_bounds__(256) void lstm_core(
    const float* __restrict__ bias, const float* __restrict__ cell,
    float* __restrict__ out,
    const _Float16* __restrict__ x16, _Float16* __restrict__ h16,
    const _Float16* __restrict__ w16)
{
  cg::grid_group grid = cg::this_grid();
  const int tid  = threadIdx.x;
  const int v    = tid >> 6;      // wave 0..3
  const int l    = tid & 63;      // lane
  const int colm = l & 15;        // m offset within tile (C col / B col / A row)
  const int krow = l >> 4;        // 0..3
  const int wg   = blockIdx.x;
  const int m0   = wg * 16;

  // bias per gate for this lane's m column
  float bf[4];
#pragma unroll
  for (int g = 0; g < 4; ++g) bf[g] = bias[g*HH + m0 + colm];

  // persistent cell state in C-fragment layout: cv[r] <-> (b = v*16 + krow*4 + r, m = m0+colm)
  float cv[4];
#pragma unroll
  for (int r = 0; r < 4; ++r)
    cv[r] = cell[(long)(v*16 + krow*4 + r)*HH + m0 + colm];

  _Float16* hbuf0 = h16;
  _Float16* hbuf1 = h16 + (long)BB*HH;

  const long wfrag_base = ((long)wg*4) * 32 * 64 * 8;  // [wg][g][kb][lane][8]

  for (int t = 0; t < T_STEPS; ++t) {
    const _Float16* hcur = (t & 1) ? hbuf1 : hbuf0;
    _Float16*       hnxt = (t & 1) ? hbuf0 : hbuf1;

    const _Float16* xp = x16 + ((long)t*BB + (v*16 + colm))*HH + krow*8;
    const _Float16* hp = hcur + (long)(v*16 + colm)*HH + krow*8;

    f32x4 acc[4];
#pragma unroll
    for (int g = 0; g < 4; ++g) {
      acc[g][0] = bf[g]; acc[g][1] = bf[g]; acc[g][2] = bf[g]; acc[g][3] = bf[g];
    }

    // K blocks 0..15: x part
#pragma unroll 4
    for (int kb = 0; kb < 16; ++kb) {
      half8 a = *(const half8*)(xp + kb*32);
#pragma unroll
      for (int g = 0; g < 4; ++g) {
        half8 bfrag = *(const half8*)(w16 + wfrag_base + (((long)g*32 + kb)*64 + l)*8);
        acc[g] = __builtin_amdgcn_mfma_f32_16x16x32_f16(a, bfrag, acc[g], 0, 0, 0);
      }
    }
    // K blocks 16..31: h part
#pragma unroll 4
    for (int kb = 16; kb < 32; ++kb) {
      half8 a = *(const half8*)(hp + (kb - 16)*32);
#pragma unroll
      for (int g = 0; g < 4; ++g) {
        half8 bfrag = *(const half8*)(w16 + wfrag_base + (((long)g*32 + kb)*64 + l)*8);
        acc[g] = __builtin_amdgcn_mfma_f32_16x16x32_f16(a, bfrag, acc[g], 0, 0, 0);
      }
    }

    // gates + state update (order: f, i, g, o)
    float hn[4];
#pragma unroll
    for (int r = 0; r < 4; ++r) {
      float zf = acc[0][r], zi = acc[1][r], zg = acc[2][r], zo = acc[3][r];
      float f  = 1.f / (1.f + __expf(-zf));
      float ig = 1.f / (1.f + __expf(-zi));
      float e  = __expf(-2.f * fabsf(zg));
      float gt = (1.f - e) / (1.f + e);
      gt = (zg < 0.f) ? -gt : gt;
      float o2 = 1.f / (1.f + __expf(-zo));
      float cn = cv[r] * f + gt * ig;
      cv[r] = cn;
      hn[r] = cn * o2;
    }

    // write h: fp32 to output slot t, fp16 to next-step buffer
    float* orow = out + (long)t*BB*HH;
#pragma unroll
    for (int r = 0; r < 4; ++r) {
      int b = v*16 + krow*4 + r;
      orow[(long)b*HH + m0 + colm] = hn[r];
      hnxt[(long)b*HH + m0 + colm] = (_Float16)hn[r];
    }

    __threadfence();
    grid.sync();
  }

  // c_last
#pragma unroll
  for (int r = 0; r < 4; ++r) {
    int b = v*16 + krow*4 + r;
    out[(long)T_STEPS*BB*HH + (long)b*HH + m0 + colm] = cv[r];
  }
}

extern "C" void kernel_launch(void* const* d_in, const int* in_sizes, int n_in,
                              void* d_out, int out_size, void* d_ws, size_t ws_size,
                              hipStream_t stream)
{
  const float* x    = (const float*)d_in[0];
  const float* h0   = (const float*)d_in[1];
  const float* c0   = (const float*)d_in[2];
  const float* W    = (const float*)d_in[3];
  const float* bias = (const float*)d_in[4];
  float* out = (float*)d_out;

  // workspace layout (halves): x16 [T*B*H], h16 [2*B*H], w16 [4H*2H packed]
  _Float16* x16 = (_Float16*)d_ws;
  _Float16* h16 = x16 + (long)T_STEPS*BB*HH;   // 33,554,432 halves
  _Float16* w16 = h16 + 2L*BB*HH;              // +65,536 halves
  // total = 71,434,240 bytes

  prep_kernel<<<dim3(2048), dim3(256), 0, stream>>>(x, h0, W, x16, h16, w16);

  void* args[] = { (void*)&bias, (void*)&c0, (void*)&out,
                   (void*)&x16, (void*)&h16, (void*)&w16 };
  hipLaunchCooperativeKernel((void*)lstm_core, dim3(NWG), dim3(256), args, 0, stream);
}

// Round 4
// 9663.261 us; speedup vs baseline: 2.1354x; 2.1354x over previous
//
#include <hip/hip_runtime.h>

typedef _Float16 half8 __attribute__((ext_vector_type(8)));
typedef float f32x4 __attribute__((ext_vector_type(4)));

#define T_STEPS 1024
#define BB 64
#define HH 512
#define NWG 32

// ---------------- prep: fp32 -> fp16 conversions, W fragment packing, h0 pack, barrier zero ----
// w16 layout: [wg][gate][kb][lane][8] halves, B-fragment order for mfma_f32_16x16x32_f16:
//   j = gate*512 + wg*16 + (lane&15), k = kb*32 + (lane>>4)*8 + e.
// hx layout: u32 [2 bufs][64 rows][256 colpairs]; u32 = f16(col even) | f16(col odd)<<16.
__global__ __launch_bounds__(256) void prep_kernel(
    const float* __restrict__ x, const float* __restrict__ h0,
    const float* __restrict__ W, _Float16* __restrict__ x16,
    unsigned* __restrict__ hx, _Float16* __restrict__ w16,
    unsigned* __restrict__ bar)
{
  const long nthr = (long)gridDim.x * blockDim.x;
  const long tid  = (long)blockIdx.x * blockDim.x + threadIdx.x;
  if (tid == 0) bar[0] = 0;

  // x: 33,554,432 halves = 8,388,608 groups of 4
  for (long p = tid; p < 8388608L; p += nthr) {
    float4 v = ((const float4*)x)[p];
    union { _Float16 h[4]; unsigned long long q; } u;
    u.h[0] = (_Float16)v.x; u.h[1] = (_Float16)v.y;
    u.h[2] = (_Float16)v.z; u.h[3] = (_Float16)v.w;
    ((unsigned long long*)x16)[p] = u.q;
  }
  // h0 -> hx buffer 0: 16384 u32
  for (long p = tid; p < 16384L; p += nthr) {
    long b = p >> 8, cu = p & 255;
    float lo = h0[b*HH + cu*2], hi = h0[b*HH + cu*2 + 1];
    unsigned short ls = __builtin_bit_cast(unsigned short, (_Float16)lo);
    unsigned short hs = __builtin_bit_cast(unsigned short, (_Float16)hi);
    hx[p] = (unsigned)ls | ((unsigned)hs << 16);
  }
  // W pack: 262,144 fragments of 8 halves
  for (long p = tid; p < 262144L; p += nthr) {
    int lane = (int)(p & 63);
    int kb   = (int)((p >> 6) & 31);
    int g    = (int)((p >> 11) & 3);
    int wg   = (int)(p >> 13);
    int j = g*512 + wg*16 + (lane & 15);
    int k = kb*32 + (lane >> 4)*8;
    const float* src = W + (long)j*1024 + k;
    float4 a = *(const float4*)(src);
    float4 b = *(const float4*)(src + 4);
    half8 o;
    o[0] = (_Float16)a.x; o[1] = (_Float16)a.y; o[2] = (_Float16)a.z; o[3] = (_Float16)a.w;
    o[4] = (_Float16)b.x; o[5] = (_Float16)b.y; o[6] = (_Float16)b.z; o[7] = (_Float16)b.w;
    *(half8*)(w16 + p*8) = o;
  }
}

// ---------------- persistent LSTM core, custom LLC barrier ----------------
// 32 wgs x 4 waves. wg owns 16 hidden cols (all 4 gates). Wave w = (khalf = w>>1, bh = w&1):
//   khalf 0 -> x half of K (kb 0..15), khalf 1 -> h half (kb 16..31)
//   bh selects batch rows [bh*32, bh*32+32) = 2 btiles of 16.
// khalf-1 waves write partials to LDS; khalf-0 waves reduce + gates + epilogue.
__global__ __launch_bounds__(256) void lstm_core(
    const float* __restrict__ bias, const float* __restrict__ cell,
    float* __restrict__ out, const _Float16* __restrict__ x16,
    unsigned* __restrict__ hx, const _Float16* __restrict__ w16,
    unsigned* __restrict__ bar)
{
  __shared__ _Float16 Wl[65536];        // 128 KB  [g][kb][lane][8]
  __shared__ f32x4 Rl[2][2][4][64];     // 16 KB   [src bh][btl][g][lane]

  const int tid  = threadIdx.x;
  const int w    = tid >> 6;
  const int l    = tid & 63;
  const int colm = l & 15;
  const int krow = l >> 4;
  const int wg   = blockIdx.x;
  const int m0   = wg * 16;
  const int khalf = w >> 1;
  const int bh    = w & 1;

  // stage this wg's W slice (128 KB) into LDS once
  {
    const unsigned long long* src = (const unsigned long long*)(w16 + (long)wg*65536);
    unsigned long long* dst = (unsigned long long*)Wl;
    for (int i = tid; i < 16384; i += 256) dst[i] = src[i];
  }
  __syncthreads();

  float bf[4];
  float cv[2][4];
  if (khalf == 0) {
#pragma unroll
    for (int g = 0; g < 4; ++g) bf[g] = bias[g*HH + m0 + colm];
#pragma unroll
    for (int bt = 0; bt < 2; ++bt)
#pragma unroll
      for (int r = 0; r < 4; ++r)
        cv[bt][r] = cell[(long)((bh*2 + bt)*16 + krow*4 + r)*HH + m0 + colm];
  }

  const unsigned long long* hx64 = (const unsigned long long*)hx;

#pragma unroll 1
  for (int t = 0; t < T_STEPS; ++t) {
    f32x4 acc[2][4];
#pragma unroll
    for (int bt = 0; bt < 2; ++bt)
#pragma unroll
      for (int g = 0; g < 4; ++g) acc[bt][g] = f32x4{0.f, 0.f, 0.f, 0.f};

    if (khalf == 0) {
      // x part: kb 0..15, A from global (L2-cached stream)
      const _Float16* xb0 = x16 + ((long)t*BB + (bh*2+0)*16 + colm)*HH + krow*8;
      const _Float16* xb1 = x16 + ((long)t*BB + (bh*2+1)*16 + colm)*HH + krow*8;
#pragma unroll 4
      for (int i = 0; i < 16; ++i) {
        half8 a0 = *(const half8*)(xb0 + i*32);
        half8 a1 = *(const half8*)(xb1 + i*32);
#pragma unroll
        for (int g = 0; g < 4; ++g) {
          half8 bfrag = *(const half8*)(Wl + ((g*32 + i)*64 + l)*8);
          acc[0][g] = __builtin_amdgcn_mfma_f32_16x16x32_f16(a0, bfrag, acc[0][g], 0, 0, 0);
          acc[1][g] = __builtin_amdgcn_mfma_f32_16x16x32_f16(a1, bfrag, acc[1][g], 0, 0, 0);
        }
      }
    } else {
      // h part: kb 16..31, A from LLC via agent-scope atomic u64 loads
      const unsigned long long* hb = hx64 + (long)(t & 1)*8192;
      const long rr0 = (long)((bh*2+0)*16 + colm)*128 + krow*2;
      const long rr1 = (long)((bh*2+1)*16 + colm)*128 + krow*2;
#pragma unroll 2
      for (int i = 0; i < 16; ++i) {
        union { unsigned long long q[2]; half8 h; } ua0, ua1;
        ua0.q[0] = __hip_atomic_load(hb + rr0 + i*8,     __ATOMIC_RELAXED, __HIP_MEMORY_SCOPE_AGENT);
        ua0.q[1] = __hip_atomic_load(hb + rr0 + i*8 + 1, __ATOMIC_RELAXED, __HIP_MEMORY_SCOPE_AGENT);
        ua1.q[0] = __hip_atomic_load(hb + rr1 + i*8,     __ATOMIC_RELAXED, __HIP_MEMORY_SCOPE_AGENT);
        ua1.q[1] = __hip_atomic_load(hb + rr1 + i*8 + 1, __ATOMIC_RELAXED, __HIP_MEMORY_SCOPE_AGENT);
#pragma unroll
        for (int g = 0; g < 4; ++g) {
          half8 bfrag = *(const half8*)(Wl + (((g*32 + 16) + i)*64 + l)*8);
          acc[0][g] = __builtin_amdgcn_mfma_f32_16x16x32_f16(ua0.h, bfrag, acc[0][g], 0, 0, 0);
          acc[1][g] = __builtin_amdgcn_mfma_f32_16x16x32_f16(ua1.h, bfrag, acc[1][g], 0, 0, 0);
        }
      }
    }

    // K-reduction: h-waves publish partials
    if (khalf == 1) {
#pragma unroll
      for (int bt = 0; bt < 2; ++bt)
#pragma unroll
        for (int g = 0; g < 4; ++g)
          Rl[bh][bt][g][l] = acc[bt][g];
    }
    __syncthreads();

    if (khalf == 0) {
#pragma unroll
      for (int bt = 0; bt < 2; ++bt)
#pragma unroll
        for (int g = 0; g < 4; ++g)
          acc[bt][g] += Rl[bh][bt][g][l];

      const long obase = (long)t*BB*HH;
      unsigned* hnx = hx + (long)((t+1) & 1)*16384;
#pragma unroll
      for (int bt = 0; bt < 2; ++bt) {
#pragma unroll
        for (int r = 0; r < 4; ++r) {
          float zf = acc[bt][0][r] + bf[0];
          float zi = acc[bt][1][r] + bf[1];
          float zg = acc[bt][2][r] + bf[2];
          float zo = acc[bt][3][r] + bf[3];
          float f  = 1.f / (1.f + __expf(-zf));
          float ii = 1.f / (1.f + __expf(-zi));
          float e  = __expf(-2.f * fabsf(zg));
          float gt = (1.f - e) / (1.f + e);
          gt = (zg < 0.f) ? -gt : gt;
          float oo = 1.f / (1.f + __expf(-zo));
          float cn = cv[bt][r] * f + gt * ii;
          cv[bt][r] = cn;
          float hn = cn * oo;
          int b = (bh*2 + bt)*16 + krow*4 + r;
          out[obase + (long)b*HH + m0 + colm] = hn;
          // pack col pair and store to next h buffer (LLC-coherent)
          float other = __shfl_xor(hn, 1, 64);
          unsigned short me = __builtin_bit_cast(unsigned short, (_Float16)hn);
          unsigned short ot = __builtin_bit_cast(unsigned short, (_Float16)other);
          if (!(l & 1)) {
            unsigned val = (unsigned)me | ((unsigned)ot << 16);
            __hip_atomic_store(hnx + (long)b*256 + ((m0 + colm) >> 1), val,
                               __ATOMIC_RELAXED, __HIP_MEMORY_SCOPE_AGENT);
          }
        }
      }
    }

    // global barrier: drain stores, wg-sync, one arrival per wg, spin at LLC
    asm volatile("s_waitcnt vmcnt(0)" ::: "memory");
    __syncthreads();
    if (tid == 0) {
      __hip_atomic_fetch_add(bar, 1u, __ATOMIC_RELAXED, __HIP_MEMORY_SCOPE_AGENT);
      const unsigned target = (unsigned)(t + 1) * NWG;
      while (__hip_atomic_load(bar, __ATOMIC_RELAXED, __HIP_MEMORY_SCOPE_AGENT) < target)
        __builtin_amdgcn_s_sleep(1);
    }
    __syncthreads();
  }

  if (khalf == 0) {
    const long cbase = (long)T_STEPS*BB*HH;
#pragma unroll
    for (int bt = 0; bt < 2; ++bt)
#pragma unroll
      for (int r = 0; r < 4; ++r) {
        int b = (bh*2 + bt)*16 + krow*4 + r;
        out[cbase + (long)b*HH + m0 + colm] = cv[bt][r];
      }
  }
}

extern "C" void kernel_launch(void* const* d_in, const int* in_sizes, int n_in,
                              void* d_out, int out_size, void* d_ws, size_t ws_size,
                              hipStream_t stream)
{
  const float* x    = (const float*)d_in[0];
  const float* h0   = (const float*)d_in[1];
  const float* c0   = (const float*)d_in[2];
  const float* W    = (const float*)d_in[3];
  const float* bias = (const float*)d_in[4];
  float* out = (float*)d_out;

  // ws layout (bytes): x16 [0, 67108864) ; w16 [67108864, 71303168) ;
  //                    hx [71303168, 71434240) ; bar [71434240, +4)
  _Float16* x16 = (_Float16*)d_ws;
  _Float16* w16 = (_Float16*)((char*)d_ws + 67108864);
  unsigned* hx  = (unsigned*)((char*)d_ws + 71303168);
  unsigned* bar = (unsigned*)((char*)d_ws + 71434240);

  prep_kernel<<<dim3(2048), dim3(256), 0, stream>>>(x, h0, W, x16, hx, w16, bar);
  lstm_core<<<dim3(NWG), dim3(256), 0, stream>>>(bias, c0, out, x16, hx, w16, bar);
}

// Round 7
// 8697.003 us; speedup vs baseline: 2.3726x; 1.1111x over previous
//
#include <hip/hip_runtime.h>

typedef _Float16 half8 __attribute__((ext_vector_type(8)));
typedef float f32x4 __attribute__((ext_vector_type(4)));
typedef unsigned u32x4 __attribute__((ext_vector_type(4)));

#define T_STEPS 1024
#define BB 64
#define HH 512
#define NWG 32

// ---------------- prep: fp32 -> fp16 conversions, W fragment packing, h0 pack, barrier zero ----
// w16 layout: [wg][gate][kb][lane][8] halves, B-fragment order for mfma_f32_16x16x32_f16:
//   j = gate*512 + wg*16 + (lane&15), k = kb*32 + (lane>>4)*8 + e.
// hx layout: u32 [2 bufs][64 rows][256 colpairs]; u32 = f16(col even) | f16(col odd)<<16.
//   (i.e. each row is 512 f16 = 1024 B, linear in k.)
__global__ __launch_bounds__(256) void prep_kernel(
    const float* __restrict__ x, const float* __restrict__ h0,
    const float* __restrict__ W, _Float16* __restrict__ x16,
    unsigned* __restrict__ hx, _Float16* __restrict__ w16,
    unsigned* __restrict__ bar)
{
  const long nthr = (long)gridDim.x * blockDim.x;
  const long tid  = (long)blockIdx.x * blockDim.x + threadIdx.x;
  if (tid == 0) bar[0] = 0;

  // x: 33,554,432 halves = 8,388,608 groups of 4
  for (long p = tid; p < 8388608L; p += nthr) {
    float4 v = ((const float4*)x)[p];
    union { _Float16 h[4]; unsigned long long q; } u;
    u.h[0] = (_Float16)v.x; u.h[1] = (_Float16)v.y;
    u.h[2] = (_Float16)v.z; u.h[3] = (_Float16)v.w;
    ((unsigned long long*)x16)[p] = u.q;
  }
  // h0 -> hx buffer 0: 16384 u32
  for (long p = tid; p < 16384L; p += nthr) {
    long b = p >> 8, cu = p & 255;
    float lo = h0[b*HH + cu*2], hi = h0[b*HH + cu*2 + 1];
    unsigned short ls = __builtin_bit_cast(unsigned short, (_Float16)lo);
    unsigned short hs = __builtin_bit_cast(unsigned short, (_Float16)hi);
    hx[p] = (unsigned)ls | ((unsigned)hs << 16);
  }
  // W pack: 262,144 fragments of 8 halves
  for (long p = tid; p < 262144L; p += nthr) {
    int lane = (int)(p & 63);
    int kb   = (int)((p >> 6) & 31);
    int g    = (int)((p >> 11) & 3);
    int wg   = (int)(p >> 13);
    int j = g*512 + wg*16 + (lane & 15);
    int k = kb*32 + (lane >> 4)*8;
    const float* src = W + (long)j*1024 + k;
    float4 a = *(const float4*)(src);
    float4 b = *(const float4*)(src + 4);
    half8 o;
    o[0] = (_Float16)a.x; o[1] = (_Float16)a.y; o[2] = (_Float16)a.z; o[3] = (_Float16)a.w;
    o[4] = (_Float16)b.x; o[5] = (_Float16)b.y; o[6] = (_Float16)b.z; o[7] = (_Float16)b.w;
    *(half8*)(w16 + p*8) = o;
  }
}

// ---------------- persistent LSTM core, custom LLC barrier ----------------
// 32 wgs x 4 waves. wg owns 16 hidden cols (all 4 gates). Wave w = (khalf = w>>1, bh = w&1):
//   khalf 0 -> x half of K (kb 0..15), khalf 1 -> h half (kb 16..31)
//   bh selects batch rows [bh*32, bh*32+32) = 2 btiles of 16.
// h is read with coalesced sc0/sc1 (LLC-coherent, L2-bypassing) dwordx4 loads,
// all 32 fragments issued up-front, one vmcnt(0) before the MFMA block.
__global__ __launch_bounds__(256) void lstm_core(
    const float* __restrict__ bias, const float* __restrict__ cell,
    float* __restrict__ out, const _Float16* __restrict__ x16,
    unsigned* __restrict__ hx, const _Float16* __restrict__ w16,
    unsigned* __restrict__ bar)
{
  __shared__ _Float16 Wl[65536];        // 128 KB  [g][kb][lane][8]
  __shared__ f32x4 Rl[2][2][4][64];     // 16 KB   [src bh][btl][g][lane]

  const int tid  = threadIdx.x;
  const int w    = tid >> 6;
  const int l    = tid & 63;
  const int colm = l & 15;
  const int krow = l >> 4;
  const int wg   = blockIdx.x;
  const int m0   = wg * 16;
  const int khalf = w >> 1;
  const int bh    = w & 1;

  // stage this wg's W slice (128 KB) into LDS once
  {
    const unsigned long long* src = (const unsigned long long*)(w16 + (long)wg*65536);
    unsigned long long* dst = (unsigned long long*)Wl;
    for (int i = tid; i < 16384; i += 256) dst[i] = src[i];
  }
  __syncthreads();

  float bf[4];
  float cv[2][4];
  if (khalf == 0) {
#pragma unroll
    for (int g = 0; g < 4; ++g) bf[g] = bias[g*HH + m0 + colm];
#pragma unroll
    for (int bt = 0; bt < 2; ++bt)
#pragma unroll
      for (int r = 0; r < 4; ++r)
        cv[bt][r] = cell[(long)((bh*2 + bt)*16 + krow*4 + r)*HH + m0 + colm];
  }

#pragma unroll 1
  for (int t = 0; t < T_STEPS; ++t) {
    f32x4 acc[2][4];
#pragma unroll
    for (int bt = 0; bt < 2; ++bt)
#pragma unroll
      for (int g = 0; g < 4; ++g) acc[bt][g] = f32x4{0.f, 0.f, 0.f, 0.f};

    if (khalf == 0) {
      // x part: kb 0..15, A from global (L2-cached stream)
      const _Float16* xb0 = x16 + ((long)t*BB + (bh*2+0)*16 + colm)*HH + krow*8;
      const _Float16* xb1 = x16 + ((long)t*BB + (bh*2+1)*16 + colm)*HH + krow*8;
#pragma unroll 4
      for (int i = 0; i < 16; ++i) {
        half8 a0 = *(const half8*)(xb0 + i*32);
        half8 a1 = *(const half8*)(xb1 + i*32);
#pragma unroll
        for (int g = 0; g < 4; ++g) {
          half8 bfrag = *(const half8*)(Wl + ((g*32 + i)*64 + l)*8);
          acc[0][g] = __builtin_amdgcn_mfma_f32_16x16x32_f16(a0, bfrag, acc[0][g], 0, 0, 0);
          acc[1][g] = __builtin_amdgcn_mfma_f32_16x16x32_f16(a1, bfrag, acc[1][g], 0, 0, 0);
        }
      }
    } else {
      // h part: kb 16..31. Coalesced LLC reads (sc0 sc1 bypasses stale L2).
      // byte addr = row*1024 + krow*16 + i*64  (identical addresses to the old
      // atomic path, but line-coalescable by the TA).
      const char* hb = (const char*)hx + (size_t)(t & 1)*65536;
      const char* p0 = hb + ((long)((bh*2+0)*16 + colm))*1024 + krow*16;
      const char* p1 = hb + ((long)((bh*2+1)*16 + colm))*1024 + krow*16;
      union { u32x4 u; half8 h; } fa0[16], fa1[16];
#pragma unroll
      for (int i = 0; i < 16; ++i) {
        asm volatile("global_load_dwordx4 %0, %1, off sc0 sc1"
                     : "=v"(fa0[i].u) : "v"(p0 + i*64) : "memory");
        asm volatile("global_load_dwordx4 %0, %1, off sc0 sc1"
                     : "=v"(fa1[i].u) : "v"(p1 + i*64) : "memory");
      }
      asm volatile("s_waitcnt vmcnt(0)" ::: "memory");
      __builtin_amdgcn_sched_barrier(0);   // keep MFMAs below the waitcnt (rule #18)
#pragma unroll
      for (int i = 0; i < 16; ++i) {
#pragma unroll
        for (int g = 0; g < 4; ++g) {
          half8 bfrag = *(const half8*)(Wl + (((g*32 + 16) + i)*64 + l)*8);
          acc[0][g] = __builtin_amdgcn_mfma_f32_16x16x32_f16(fa0[i].h, bfrag, acc[0][g], 0, 0, 0);
          acc[1][g] = __builtin_amdgcn_mfma_f32_16x16x32_f16(fa1[i].h, bfrag, acc[1][g], 0, 0, 0);
        }
      }
    }

    // K-reduction: h-waves publish partials
    if (khalf == 1) {
#pragma unroll
      for (int bt = 0; bt < 2; ++bt)
#pragma unroll
        for (int g = 0; g < 4; ++g)
          Rl[bh][bt][g][l] = acc[bt][g];
    }
    __syncthreads();

    if (khalf == 0) {
#pragma unroll
      for (int bt = 0; bt < 2; ++bt)
#pragma unroll
        for (int g = 0; g < 4; ++g)
          acc[bt][g] += Rl[bh][bt][g][l];

      const long obase = (long)t*BB*HH;
      unsigned* hnx = hx + (long)((t+1) & 1)*16384;
#pragma unroll
      for (int bt = 0; bt < 2; ++bt) {
#pragma unroll
        for (int r = 0; r < 4; ++r) {
          float zf = acc[bt][0][r] + bf[0];
          float zi = acc[bt][1][r] + bf[1];
          float zg = acc[bt][2][r] + bf[2];
          float zo = acc[bt][3][r] + bf[3];
          float f  = 1.f / (1.f + __expf(-zf));
          float ii = 1.f / (1.f + __expf(-zi));
          float e  = __expf(-2.f * fabsf(zg));
          float gt = (1.f - e) / (1.f + e);
          gt = (zg < 0.f) ? -gt : gt;
          float oo = 1.f / (1.f + __expf(-zo));
          float cn = cv[bt][r] * f + gt * ii;
          cv[bt][r] = cn;
          float hn = cn * oo;
          int b = (bh*2 + bt)*16 + krow*4 + r;
          out[obase + (long)b*HH + m0 + colm] = hn;
          // pack col pair and store to next h buffer (LLC-coherent)
          float other = __shfl_xor(hn, 1, 64);
          unsigned short me = __builtin_bit_cast(unsigned short, (_Float16)hn);
          unsigned short ot = __builtin_bit_cast(unsigned short, (_Float16)other);
          if (!(l & 1)) {
            unsigned val = (unsigned)me | ((unsigned)ot << 16);
            __hip_atomic_store(hnx + (long)b*256 + ((m0 + colm) >> 1), val,
                               __ATOMIC_RELAXED, __HIP_MEMORY_SCOPE_AGENT);
          }
        }
      }
    }

    // global barrier: drain stores, wg-sync, one arrival per wg, spin at LLC
    asm volatile("s_waitcnt vmcnt(0)" ::: "memory");
    __syncthreads();
    if (tid == 0) {
      __hip_atomic_fetch_add(bar, 1u, __ATOMIC_RELAXED, __HIP_MEMORY_SCOPE_AGENT);
      const unsigned target = (unsigned)(t + 1) * NWG;
      while (__hip_atomic_load(bar, __ATOMIC_RELAXED, __HIP_MEMORY_SCOPE_AGENT) < target)
        __builtin_amdgcn_s_sleep(1);
    }
    __syncthreads();
  }

  if (khalf == 0) {
    const long cbase = (long)T_STEPS*BB*HH;
#pragma unroll
    for (int bt = 0; bt < 2; ++bt)
#pragma unroll
      for (int r = 0; r < 4; ++r) {
        int b = (bh*2 + bt)*16 + krow*4 + r;
        out[cbase + (long)b*HH + m0 + colm] = cv[bt][r];
      }
  }
}

extern "C" void kernel_launch(void* const* d_in, const int* in_sizes, int n_in,
                              void* d_out, int out_size, void* d_ws, size_t ws_size,
                              hipStream_t stream)
{
  const float* x    = (const float*)d_in[0];
  const float* h0   = (const float*)d_in[1];
  const float* c0   = (const float*)d_in[2];
  const float* W    = (const float*)d_in[3];
  const float* bias = (const float*)d_in[4];
  float* out = (float*)d_out;

  // ws layout (bytes): x16 [0, 67108864) ; w16 [67108864, 71303168) ;
  //                    hx [71303168, 71434240) ; bar [71434240, +4)
  _Float16* x16 = (_Float16*)d_ws;
  _Float16* w16 = (_Float16*)((char*)d_ws + 67108864);
  unsigned* hx  = (unsigned*)((char*)d_ws + 71303168);
  unsigned* bar = (unsigned*)((char*)d_ws + 71434240);

  prep_kernel<<<dim3(2048), dim3(256), 0, stream>>>(x, h0, W, x16, hx, w16, bar);
  lstm_core<<<dim3(NWG), dim3(256), 0, stream>>>(bias, c0, out, x16, hx, w16, bar);
}